// Round 4
// baseline (687.375 us; speedup 1.0000x reference)
//
#include <hip/hip_runtime.h>
#include <math.h>

#define TIME_N 65536
#define WIN    2048
#define HALFN  1024
#define NBINS  1025
#define NFRAMES 64
#define FCHUNK 8
#define NCHUNK (NFRAMES / FCHUNK)   // 8

// ---------------------------------------------------------------------------
// Kernel 1: channel mixing  out[b,d,t] = sum_c x[b,c,t] * M[c,d]
// ---------------------------------------------------------------------------
#define TT 128
__global__ __launch_bounds__(256) void mix_kernel(const float* __restrict__ x,
                                                  const float* __restrict__ M,
                                                  float* __restrict__ out) {
    __shared__ float Ml[64 * 64];
    __shared__ float xt[64][136];
    const int b   = blockIdx.y;
    const int t0  = blockIdx.x * TT;
    const int tid = threadIdx.x;

    for (int i = tid; i < 64 * 64; i += 256) Ml[i] = M[i];

    for (int r = 0; r < 8; ++r) {
        int fi = tid + r * 256;
        int c  = fi >> 5;
        int t4 = fi & 31;
        float4 v = *reinterpret_cast<const float4*>(
            x + (size_t)(b * 64 + c) * TIME_N + t0 + t4 * 4);
        *reinterpret_cast<float4*>(&xt[c][t4 * 4]) = v;
    }
    __syncthreads();

    const int dq = tid >> 5;
    const int tq = tid & 31;

    float acc[8][4];
#pragma unroll
    for (int i = 0; i < 8; ++i)
#pragma unroll
        for (int j = 0; j < 4; ++j) acc[i][j] = 0.f;

    for (int c = 0; c < 64; ++c) {
        float xv[4];
#pragma unroll
        for (int j = 0; j < 4; ++j) xv[j] = xt[c][tq + 32 * j];
#pragma unroll
        for (int i = 0; i < 8; ++i) {
            float mv = Ml[c * 64 + dq * 8 + i];
#pragma unroll
            for (int j = 0; j < 4; ++j) acc[i][j] += xv[j] * mv;
        }
    }

#pragma unroll
    for (int i = 0; i < 8; ++i) {
        int d = dq * 8 + i;
        size_t baseo = (size_t)(b * 64 + d) * TIME_N + t0;
#pragma unroll
        for (int j = 0; j < 4; ++j) out[baseo + tq + 32 * j] = acc[i][j];
    }
}

// ---------------------------------------------------------------------------
// Kernel 2: fused STFT -> per-bin frame recursion -> iSTFT -> OLA -> tanh.
// 256 blocks x 1024 threads; 8 frames per chunk; ping-pong Stockham radix-4
// (1 barrier/stage); per-bin scan carry + transfer + OLA tail in registers;
// register prefetch of next chunk's samples.
// __launch_bounds__(1024, 4): 16 waves/CU = our exact occupancy (LDS-bound
// at 1 block/CU) -> VGPR cap 128, eliminating the round-3 scratch spills.
// ---------------------------------------------------------------------------
__device__ __forceinline__ int P(int i) { return i + (i >> 4); }   // pad-16
#define BUFSZ 1088   // P(1023) = 1086

__device__ __forceinline__ float2 cadd(float2 a, float2 b){return make_float2(a.x+b.x, a.y+b.y);}
__device__ __forceinline__ float2 csub(float2 a, float2 b){return make_float2(a.x-b.x, a.y-b.y);}
__device__ __forceinline__ float2 cmul(float2 a, float2 b){return make_float2(a.x*b.x - a.y*b.y, a.x*b.y + a.y*b.x);}

// One radix-4 self-sorting stage: read src, write dst (ping-pong).
// lt in [0,128): butterflies lt and lt+128.  k = stage (0..4).
template<int SGN>
__device__ __forceinline__ void fft_stage(const float2* __restrict__ src,
                                          float2* __restrict__ dst,
                                          int lt, int k) {
    const float PI2 = 6.2831853071795864769f;
    const int s = 1 << (2 * k);
    const int n = 1024 >> (2 * k);
#pragma unroll
    for (int r = 0; r < 2; ++r) {
        const int i = lt + r * 128;
        const int p = i >> (2 * k);
        const int q = i & (s - 1);
        float2 a  = src[P(i)];
        float2 bv = src[P(i + 256)];
        float2 cv = src[P(i + 512)];
        float2 dv = src[P(i + 768)];
        float ang = (float)SGN * PI2 * (float)p / (float)n;
        float sn, cs; __sincosf(ang, &sn, &cs);
        float2 w1 = make_float2(cs, sn);
        float2 w2 = cmul(w1, w1);
        float2 w3 = cmul(w1, w2);
        float2 apc = cadd(a, cv), amc = csub(a, cv);
        float2 bpd = cadd(bv, dv), bmd = csub(bv, dv);
        float2 sj = make_float2(-(float)SGN * bmd.y, (float)SGN * bmd.x);
        float2 y0 = cadd(apc, bpd);
        float2 y1 = cmul(w1, cadd(amc, sj));
        float2 y2 = cmul(w2, csub(apc, bpd));
        float2 y3 = cmul(w3, csub(amc, sj));
        int wb = q + 4 * s * p;
        dst[P(wb)]         = y0;
        dst[P(wb + s)]     = y1;
        dst[P(wb + 2 * s)] = y2;
        dst[P(wb + 3 * s)] = y3;
    }
}

__global__ __launch_bounds__(1024, 4) void stft_chain_kernel(
    const float* __restrict__ transfer,
    const float* __restrict__ gainp,
    float* __restrict__ io)
{
    __shared__ float2 bufs[2][FCHUNK][BUFSZ];   // 136 KB ping-pong
    __shared__ float2 onys[FCHUNK];

    const int bd  = blockIdx.x;        // 0..255
    const int d   = bd & 63;
    const int tid = threadIdx.x;       // 0..1023
    const int lf  = tid >> 7;          // frame within chunk (0..7)
    const int lt  = tid & 127;         // butterfly lane within that FFT
    const float g = gainp[0];
    const size_t base = (size_t)bd * TIME_N;
    const float PI  = 3.14159265358979323846f;
    const float inv = 1.0f / 1024.0f;

    // --- persistent per-thread state ---
    const float Treg = transfer[(size_t)d * NBINS + tid];
    const float Tny  = (tid == 0) ? transfer[(size_t)d * NBINS + HALFN] : 0.f;
    float2 C   = make_float2(0.f, 0.f);
    float2 Cny = make_float2(0.f, 0.f);
    float tailr = 0.f;

    // --- window / twiddle constants ---
    const float wA  = 0.5f - 0.5f * __cosf((PI / HALFN) * (float)(2 * tid));
    const float wB  = 0.5f - 0.5f * __cosf((PI / HALFN) * (float)(2 * tid + 1));
    const float wU0 = 0.5f - 0.5f * __cosf((PI / HALFN) * (float)tid);
    const float wU1 = 0.5f - 0.5f * __cosf((PI / HALFN) * (float)(HALFN + tid));
    float s2v, c2v; __sincosf((PI / HALFN) * (float)tid, &s2v, &c2v);
    const float e2c = c2v, e2s = -s2v;       // e^{-i pi k/1024}

    // --- initial prefetch (chunk 0) ---
    float2 pre[FCHUNK];
#pragma unroll
    for (int f = 0; f < FCHUNK; ++f) {
        int t = f * HALFN + 2 * tid;
        pre[f] = *reinterpret_cast<const float2*>(io + base + t);  // in range for ch=0
    }

    for (int ch = 0; ch < NCHUNK; ++ch) {
        // ---------- window + store to bufs[0] ----------
#pragma unroll
        for (int f = 0; f < FCHUNK; ++f) {
            float2 v = pre[f];
            v.x *= wA; v.y *= wB;
            bufs[0][f][P(tid)] = v;
        }
        __syncthreads();

        // ---------- prefetch next chunk (disjoint from this chunk's writes) --
        if (ch + 1 < NCHUNK) {
#pragma unroll
            for (int f = 0; f < FCHUNK; ++f) {
                int t = (ch + 1) * (FCHUNK * HALFN) + f * HALFN + 2 * tid;
                float2 v = make_float2(0.f, 0.f);
                if (t < TIME_N)
                    v = *reinterpret_cast<const float2*>(io + base + t);
                pre[f] = v;
            }
        }

        // ---------- forward FFTs (ping-pong, 1 barrier/stage) ----------
        {
            int cur = 0;
#pragma unroll
            for (int k = 0; k < 5; ++k) {
                fft_stage<-1>(&bufs[cur][lf][0], &bufs[cur ^ 1][lf][0], lt, k);
                __syncthreads();
                cur ^= 1;
            }
        }
        // forward result in bufs[1]

        // ---------- rfft post-process + per-bin scan (regs) -> bufs[0] ----
#pragma unroll
        for (int f = 0; f < FCHUNK; ++f) {
            float2 Zk = bufs[1][f][P(tid)];
            float2 Zn = bufs[1][f][P((HALFN - tid) & (HALFN - 1))];
            float2 Fe = make_float2(0.5f * (Zk.x + Zn.x), 0.5f * (Zk.y - Zn.y));
            float2 Fo = make_float2(0.5f * (Zk.y + Zn.y), -0.5f * (Zk.x - Zn.x));
            float2 X  = cmul(make_float2(e2c, e2s), Fo);
            X.x += Fe.x; X.y += Fe.y;
            C.x = (X.x + C.x) * Treg;
            C.y = (X.y + C.y) * Treg;
            bufs[0][f][P(tid)] = C;
            if (tid == 0) {
                float Xny = Zk.x - Zk.y;            // from z[0]
                Cny.x = (Xny + Cny.x) * Tny;
                Cny.y = Cny.y * Tny;
                onys[f] = Cny;
            }
        }
        __syncthreads();

        // ---------- irfft pre-process: bufs[0] -> bufs[1] ----------
#pragma unroll
        for (int f = 0; f < FCHUNK; ++f) {
            float2 Om = bufs[0][f][P(tid)];
            float2 On = (tid == 0) ? onys[f] : bufs[0][f][P(HALFN - tid)];
            float2 Fe  = make_float2(0.5f * (Om.x + On.x), 0.5f * (Om.y - On.y));
            float2 num = make_float2(0.5f * (Om.x - On.x), 0.5f * (Om.y + On.y));
            float2 Fo  = cmul(make_float2(e2c, -e2s), num);  // e^{+i pi m/1024}
            bufs[1][f][P(tid)] = make_float2(Fe.x - Fo.y, Fe.y + Fo.x);
        }
        __syncthreads();

        // ---------- inverse FFTs (ping-pong) ----------
        {
            int cur = 1;
#pragma unroll
            for (int k = 0; k < 5; ++k) {
                fft_stage<1>(&bufs[cur][lf][0], &bufs[cur ^ 1][lf][0], lt, k);
                __syncthreads();
                cur ^= 1;
            }
        }
        // inverse result in bufs[0]

        // ---------- unpack + OLA + gain + tanh ----------
#pragma unroll
        for (int f = 0; f < FCHUNK; ++f) {
            int fr = ch * FCHUNK + f;
            float2 zlo = bufs[0][f][P(tid >> 1)];
            float2 zhi = bufs[0][f][P(512 + (tid >> 1))];
            float xs = (tid & 1) ? zlo.y : zlo.x;
            float xh = (tid & 1) ? zhi.y : zhi.x;
            float v  = tailr + xs * inv * wU0;
            io[base + (size_t)fr * HALFN + tid] = tanhf(g * v);
            tailr = xh * inv * wU1;
        }
        __syncthreads();   // protect bufs[0] before next chunk's window-store
    }
}

// ---------------------------------------------------------------------------
extern "C" void kernel_launch(void* const* d_in, const int* in_sizes, int n_in,
                              void* d_out, int out_size, void* d_ws, size_t ws_size,
                              hipStream_t stream) {
    const float* x        = (const float*)d_in[0];   // (4,64,65536)
    const float* transfer = (const float*)d_in[1];   // (64,1025)
    const float* mixer    = (const float*)d_in[2];   // (64,64)
    const float* gain     = (const float*)d_in[3];   // (1,)
    float* out = (float*)d_out;                      // (4,64,65536)

    dim3 g1(TIME_N / TT, 4);
    mix_kernel<<<g1, 256, 0, stream>>>(x, mixer, out);

    stft_chain_kernel<<<256, 1024, 0, stream>>>(transfer, gain, out);
}

// Round 5
// 482.364 us; speedup vs baseline: 1.4250x; 1.4250x over previous
//
#include <hip/hip_runtime.h>
#include <math.h>

#define TIME_N 65536
#define WIN    2048
#define HALFN  1024
#define NBINS  1025
#define NFRAMES 64
#define FCHUNK 8
#define NCHUNK (NFRAMES / FCHUNK)   // 8

// ---------------------------------------------------------------------------
// Kernel 1: channel mixing  out[b,d,t] = sum_c x[b,c,t] * M[c,d]
// ---------------------------------------------------------------------------
#define TT 128
__global__ __launch_bounds__(256) void mix_kernel(const float* __restrict__ x,
                                                  const float* __restrict__ M,
                                                  float* __restrict__ out) {
    __shared__ float Ml[64 * 64];
    __shared__ float xt[64][136];
    const int b   = blockIdx.y;
    const int t0  = blockIdx.x * TT;
    const int tid = threadIdx.x;

    for (int i = tid; i < 64 * 64; i += 256) Ml[i] = M[i];

    for (int r = 0; r < 8; ++r) {
        int fi = tid + r * 256;
        int c  = fi >> 5;
        int t4 = fi & 31;
        float4 v = *reinterpret_cast<const float4*>(
            x + (size_t)(b * 64 + c) * TIME_N + t0 + t4 * 4);
        *reinterpret_cast<float4*>(&xt[c][t4 * 4]) = v;
    }
    __syncthreads();

    const int dq = tid >> 5;
    const int tq = tid & 31;

    float acc[8][4];
#pragma unroll
    for (int i = 0; i < 8; ++i)
#pragma unroll
        for (int j = 0; j < 4; ++j) acc[i][j] = 0.f;

    for (int c = 0; c < 64; ++c) {
        float xv[4];
#pragma unroll
        for (int j = 0; j < 4; ++j) xv[j] = xt[c][tq + 32 * j];
#pragma unroll
        for (int i = 0; i < 8; ++i) {
            float mv = Ml[c * 64 + dq * 8 + i];
#pragma unroll
            for (int j = 0; j < 4; ++j) acc[i][j] += xv[j] * mv;
        }
    }

#pragma unroll
    for (int i = 0; i < 8; ++i) {
        int d = dq * 8 + i;
        size_t baseo = (size_t)(b * 64 + d) * TIME_N + t0;
#pragma unroll
        for (int j = 0; j < 4; ++j) out[baseo + tq + 32 * j] = acc[i][j];
    }
}

// ---------------------------------------------------------------------------
// Kernel 2: fused STFT -> per-bin frame recursion -> iSTFT -> OLA -> tanh.
// 256 blocks x 1024 threads; 8 frames per chunk; ping-pong Stockham radix-4
// (1 barrier/stage); scan carry + transfer + OLA tail in registers.
// amdgpu_waves_per_eu(4,4): grid==256==#CUs and 136KB LDS -> exactly 1 block
// (16 waves) per CU; pinning the occupancy target at 4 waves/EU gives the
// allocator a 128-VGPR budget, eliminating the scratch spills of rounds 2-4.
// No register prefetch (16 fewer live VGPRs; it bought nothing).
// ---------------------------------------------------------------------------
__device__ __forceinline__ int P(int i) { return i + (i >> 4); }   // pad-16
#define BUFSZ 1088   // P(1023) = 1086

__device__ __forceinline__ float2 cadd(float2 a, float2 b){return make_float2(a.x+b.x, a.y+b.y);}
__device__ __forceinline__ float2 csub(float2 a, float2 b){return make_float2(a.x-b.x, a.y-b.y);}
__device__ __forceinline__ float2 cmul(float2 a, float2 b){return make_float2(a.x*b.x - a.y*b.y, a.x*b.y + a.y*b.x);}

// One radix-4 self-sorting stage: read src, write dst (ping-pong).
// lt in [0,128): butterflies lt and lt+128.  k = stage (0..4).
template<int SGN>
__device__ __forceinline__ void fft_stage(const float2* __restrict__ src,
                                          float2* __restrict__ dst,
                                          int lt, int k) {
    const float PI2 = 6.2831853071795864769f;
    const int s = 1 << (2 * k);
    const int n = 1024 >> (2 * k);
#pragma unroll
    for (int r = 0; r < 2; ++r) {
        const int i = lt + r * 128;
        const int p = i >> (2 * k);
        const int q = i & (s - 1);
        float2 a  = src[P(i)];
        float2 bv = src[P(i + 256)];
        float2 cv = src[P(i + 512)];
        float2 dv = src[P(i + 768)];
        float ang = (float)SGN * PI2 * (float)p / (float)n;
        float sn, cs; __sincosf(ang, &sn, &cs);
        float2 w1 = make_float2(cs, sn);
        float2 w2 = cmul(w1, w1);
        float2 w3 = cmul(w1, w2);
        float2 apc = cadd(a, cv), amc = csub(a, cv);
        float2 bpd = cadd(bv, dv), bmd = csub(bv, dv);
        float2 sj = make_float2(-(float)SGN * bmd.y, (float)SGN * bmd.x);
        float2 y0 = cadd(apc, bpd);
        float2 y1 = cmul(w1, cadd(amc, sj));
        float2 y2 = cmul(w2, csub(apc, bpd));
        float2 y3 = cmul(w3, csub(amc, sj));
        int wb = q + 4 * s * p;
        dst[P(wb)]         = y0;
        dst[P(wb + s)]     = y1;
        dst[P(wb + 2 * s)] = y2;
        dst[P(wb + 3 * s)] = y3;
    }
}

__global__ __launch_bounds__(1024)
__attribute__((amdgpu_waves_per_eu(4, 4)))
void stft_chain_kernel(
    const float* __restrict__ transfer,
    const float* __restrict__ gainp,
    float* __restrict__ io)
{
    __shared__ float2 bufs[2][FCHUNK][BUFSZ];   // 136 KB ping-pong
    __shared__ float2 onys[FCHUNK];

    const int bd  = blockIdx.x;        // 0..255
    const int d   = bd & 63;
    const int tid = threadIdx.x;       // 0..1023
    const int lf  = tid >> 7;          // frame within chunk (0..7)
    const int lt  = tid & 127;         // butterfly lane within that FFT
    const float g = gainp[0];
    const size_t base = (size_t)bd * TIME_N;
    const float PI  = 3.14159265358979323846f;
    const float inv = 1.0f / 1024.0f;

    // --- persistent per-thread state ---
    const float Treg = transfer[(size_t)d * NBINS + tid];
    const float Tny  = (tid == 0) ? transfer[(size_t)d * NBINS + HALFN] : 0.f;
    float2 C   = make_float2(0.f, 0.f);
    float2 Cny = make_float2(0.f, 0.f);
    float tailr = 0.f;

    // --- window / twiddle constants ---
    const float wA  = 0.5f - 0.5f * __cosf((PI / HALFN) * (float)(2 * tid));
    const float wB  = 0.5f - 0.5f * __cosf((PI / HALFN) * (float)(2 * tid + 1));
    const float wU0 = 0.5f - 0.5f * __cosf((PI / HALFN) * (float)tid);
    const float wU1 = 0.5f - 0.5f * __cosf((PI / HALFN) * (float)(HALFN + tid));
    float s2v, c2v; __sincosf((PI / HALFN) * (float)tid, &s2v, &c2v);
    const float e2c = c2v, e2s = -s2v;       // e^{-i pi k/1024}

    for (int ch = 0; ch < NCHUNK; ++ch) {
        // ---------- load + window + store to bufs[0] ----------
#pragma unroll
        for (int f = 0; f < FCHUNK; ++f) {
            int fr = ch * FCHUNK + f;
            int t  = fr * HALFN + 2 * tid;
            float2 v = make_float2(0.f, 0.f);
            if (t < TIME_N)
                v = *reinterpret_cast<const float2*>(io + base + t);
            v.x *= wA; v.y *= wB;
            bufs[0][f][P(tid)] = v;
        }
        __syncthreads();

        // ---------- forward FFTs (ping-pong, 1 barrier/stage) ----------
        {
            int cur = 0;
#pragma unroll
            for (int k = 0; k < 5; ++k) {
                fft_stage<-1>(&bufs[cur][lf][0], &bufs[cur ^ 1][lf][0], lt, k);
                __syncthreads();
                cur ^= 1;
            }
        }
        // forward result in bufs[1]

        // ---------- rfft post-process + per-bin scan (regs) -> bufs[0] ----
#pragma unroll
        for (int f = 0; f < FCHUNK; ++f) {
            float2 Zk = bufs[1][f][P(tid)];
            float2 Zn = bufs[1][f][P((HALFN - tid) & (HALFN - 1))];
            float2 Fe = make_float2(0.5f * (Zk.x + Zn.x), 0.5f * (Zk.y - Zn.y));
            float2 Fo = make_float2(0.5f * (Zk.y + Zn.y), -0.5f * (Zk.x - Zn.x));
            float2 X  = cmul(make_float2(e2c, e2s), Fo);
            X.x += Fe.x; X.y += Fe.y;
            C.x = (X.x + C.x) * Treg;
            C.y = (X.y + C.y) * Treg;
            bufs[0][f][P(tid)] = C;
            if (tid == 0) {
                float Xny = Zk.x - Zk.y;            // from z[0]
                Cny.x = (Xny + Cny.x) * Tny;
                Cny.y = Cny.y * Tny;
                onys[f] = Cny;
            }
        }
        __syncthreads();

        // ---------- irfft pre-process: bufs[0] -> bufs[1] ----------
#pragma unroll
        for (int f = 0; f < FCHUNK; ++f) {
            float2 Om = bufs[0][f][P(tid)];
            float2 On = (tid == 0) ? onys[f] : bufs[0][f][P(HALFN - tid)];
            float2 Fe  = make_float2(0.5f * (Om.x + On.x), 0.5f * (Om.y - On.y));
            float2 num = make_float2(0.5f * (Om.x - On.x), 0.5f * (Om.y + On.y));
            float2 Fo  = cmul(make_float2(e2c, -e2s), num);  // e^{+i pi m/1024}
            bufs[1][f][P(tid)] = make_float2(Fe.x - Fo.y, Fe.y + Fo.x);
        }
        __syncthreads();

        // ---------- inverse FFTs (ping-pong) ----------
        {
            int cur = 1;
#pragma unroll
            for (int k = 0; k < 5; ++k) {
                fft_stage<1>(&bufs[cur][lf][0], &bufs[cur ^ 1][lf][0], lt, k);
                __syncthreads();
                cur ^= 1;
            }
        }
        // inverse result in bufs[0]

        // ---------- unpack + OLA + gain + tanh ----------
#pragma unroll
        for (int f = 0; f < FCHUNK; ++f) {
            int fr = ch * FCHUNK + f;
            float2 zlo = bufs[0][f][P(tid >> 1)];
            float2 zhi = bufs[0][f][P(512 + (tid >> 1))];
            float xs = (tid & 1) ? zlo.y : zlo.x;
            float xh = (tid & 1) ? zhi.y : zhi.x;
            float v  = tailr + xs * inv * wU0;
            io[base + (size_t)fr * HALFN + tid] = tanhf(g * v);
            tailr = xh * inv * wU1;
        }
        __syncthreads();   // protect bufs[0] before next chunk's window-store
    }
}

// ---------------------------------------------------------------------------
extern "C" void kernel_launch(void* const* d_in, const int* in_sizes, int n_in,
                              void* d_out, int out_size, void* d_ws, size_t ws_size,
                              hipStream_t stream) {
    const float* x        = (const float*)d_in[0];   // (4,64,65536)
    const float* transfer = (const float*)d_in[1];   // (64,1025)
    const float* mixer    = (const float*)d_in[2];   // (64,64)
    const float* gain     = (const float*)d_in[3];   // (1,)
    float* out = (float*)d_out;                      // (4,64,65536)

    dim3 g1(TIME_N / TT, 4);
    mix_kernel<<<g1, 256, 0, stream>>>(x, mixer, out);

    stft_chain_kernel<<<256, 1024, 0, stream>>>(transfer, gain, out);
}

// Round 6
// 243.567 us; speedup vs baseline: 2.8221x; 1.9804x over previous
//
#include <hip/hip_runtime.h>
#include <math.h>

#define TIME_N 65536
#define WIN    2048
#define HALFN  1024
#define NBINS  1025
#define NFRAMES 64
#define FCHUNK 4
#define NCHUNK (NFRAMES / FCHUNK)   // 16

// ---------------------------------------------------------------------------
// Kernel 1: channel mixing  out[b,d,t] = sum_c x[b,c,t] * M[c,d]
// ---------------------------------------------------------------------------
#define TT 128
__global__ __launch_bounds__(256) void mix_kernel(const float* __restrict__ x,
                                                  const float* __restrict__ M,
                                                  float* __restrict__ out) {
    __shared__ float Ml[64 * 64];
    __shared__ float xt[64][136];
    const int b   = blockIdx.y;
    const int t0  = blockIdx.x * TT;
    const int tid = threadIdx.x;

    for (int i = tid; i < 64 * 64; i += 256) Ml[i] = M[i];

    for (int r = 0; r < 8; ++r) {
        int fi = tid + r * 256;
        int c  = fi >> 5;
        int t4 = fi & 31;
        float4 v = *reinterpret_cast<const float4*>(
            x + (size_t)(b * 64 + c) * TIME_N + t0 + t4 * 4);
        *reinterpret_cast<float4*>(&xt[c][t4 * 4]) = v;
    }
    __syncthreads();

    const int dq = tid >> 5;
    const int tq = tid & 31;

    float acc[8][4];
#pragma unroll
    for (int i = 0; i < 8; ++i)
#pragma unroll
        for (int j = 0; j < 4; ++j) acc[i][j] = 0.f;

    for (int c = 0; c < 64; ++c) {
        float xv[4];
#pragma unroll
        for (int j = 0; j < 4; ++j) xv[j] = xt[c][tq + 32 * j];
#pragma unroll
        for (int i = 0; i < 8; ++i) {
            float mv = Ml[c * 64 + dq * 8 + i];
#pragma unroll
            for (int j = 0; j < 4; ++j) acc[i][j] += xv[j] * mv;
        }
    }

#pragma unroll
    for (int i = 0; i < 8; ++i) {
        int d = dq * 8 + i;
        size_t baseo = (size_t)(b * 64 + d) * TIME_N + t0;
#pragma unroll
        for (int j = 0; j < 4; ++j) out[baseo + tq + 32 * j] = acc[i][j];
    }
}

// ---------------------------------------------------------------------------
// Kernel 2: fused STFT -> per-bin frame recursion -> iSTFT -> OLA -> tanh.
// 256 blocks x 1024 threads; FCHUNK=4 frames per chunk (256 threads per FFT,
// ONE radix-4 butterfly per thread -> low register pressure, fits the 64-VGPR
// budget with no scratch spill); ping-pong Stockham (1 barrier/stage);
// per-frame glue phases (no cross-barrier register arrays); scan carry +
// transfer + OLA tail in registers.
// ---------------------------------------------------------------------------
__device__ __forceinline__ int P(int i) { return i + (i >> 4); }   // pad-16
#define BUFSZ 1088   // P(1023) = 1086

__device__ __forceinline__ float2 cadd(float2 a, float2 b){return make_float2(a.x+b.x, a.y+b.y);}
__device__ __forceinline__ float2 csub(float2 a, float2 b){return make_float2(a.x-b.x, a.y-b.y);}
__device__ __forceinline__ float2 cmul(float2 a, float2 b){return make_float2(a.x*b.x - a.y*b.y, a.x*b.y + a.y*b.x);}

// One radix-4 self-sorting Stockham stage: read src, write dst (ping-pong).
// lt in [0,256): one butterfly per thread.  k = stage (0..4).
template<int SGN>
__device__ __forceinline__ void fft_stage(const float2* __restrict__ src,
                                          float2* __restrict__ dst,
                                          int lt, int k) {
    const float PI2 = 6.2831853071795864769f;
    const int s = 1 << (2 * k);
    const int n = 1024 >> (2 * k);
    const int p = lt >> (2 * k);
    const int q = lt & (s - 1);
    float2 a  = src[P(lt)];
    float2 bv = src[P(lt + 256)];
    float2 cv = src[P(lt + 512)];
    float2 dv = src[P(lt + 768)];
    float ang = (float)SGN * PI2 * (float)p / (float)n;
    float sn, cs; __sincosf(ang, &sn, &cs);
    float2 w1 = make_float2(cs, sn);
    float2 w2 = cmul(w1, w1);
    float2 w3 = cmul(w1, w2);
    float2 apc = cadd(a, cv), amc = csub(a, cv);
    float2 bpd = cadd(bv, dv), bmd = csub(bv, dv);
    float2 sj = make_float2(-(float)SGN * bmd.y, (float)SGN * bmd.x);
    float2 y0 = cadd(apc, bpd);
    float2 y1 = cmul(w1, cadd(amc, sj));
    float2 y2 = cmul(w2, csub(apc, bpd));
    float2 y3 = cmul(w3, csub(amc, sj));
    int wb = q + 4 * s * p;
    dst[P(wb)]         = y0;
    dst[P(wb + s)]     = y1;
    dst[P(wb + 2 * s)] = y2;
    dst[P(wb + 3 * s)] = y3;
}

__global__ __launch_bounds__(1024, 4) void stft_chain_kernel(
    const float* __restrict__ transfer,
    const float* __restrict__ gainp,
    float* __restrict__ io)
{
    __shared__ float2 bufs[2][FCHUNK][BUFSZ];   // 68 KB ping-pong
    __shared__ float2 onys[FCHUNK];

    const int bd  = blockIdx.x;        // 0..255
    const int d   = bd & 63;
    const int tid = threadIdx.x;       // 0..1023
    const int lf  = tid >> 8;          // frame within chunk (0..3)
    const int lt  = tid & 255;         // butterfly lane within that FFT
    const float g = gainp[0];
    const size_t base = (size_t)bd * TIME_N;
    const float PI  = 3.14159265358979323846f;
    const float inv = 1.0f / 1024.0f;

    // --- persistent per-thread state (kept deliberately small) ---
    const float Treg = transfer[(size_t)d * NBINS + tid];
    const float Tny  = (tid == 0) ? transfer[(size_t)d * NBINS + HALFN] : 0.f;
    float2 C   = make_float2(0.f, 0.f);
    float2 Cny = make_float2(0.f, 0.f);
    float tailr = 0.f;
    float s2v, c2v; __sincosf((PI / HALFN) * (float)tid, &s2v, &c2v);
    const float e2c = c2v, e2s = -s2v;       // e^{-i pi k/1024}

    for (int ch = 0; ch < NCHUNK; ++ch) {
        // ---------- load + window + store to bufs[0] ----------
        {
            float swA, cwA, swB, cwB;
            __sincosf((PI / HALFN) * (float)(2 * tid), &swA, &cwA);
            __sincosf((PI / HALFN) * (float)(2 * tid + 1), &swB, &cwB);
            float wA = 0.5f - 0.5f * cwA;
            float wB = 0.5f - 0.5f * cwB;
#pragma unroll
            for (int f = 0; f < FCHUNK; ++f) {
                int fr = ch * FCHUNK + f;
                int t  = fr * HALFN + 2 * tid;
                float2 v = make_float2(0.f, 0.f);
                if (t < TIME_N)
                    v = *reinterpret_cast<const float2*>(io + base + t);
                v.x *= wA; v.y *= wB;
                bufs[0][f][P(tid)] = v;
            }
        }
        __syncthreads();

        // ---------- forward FFTs (ping-pong, 1 barrier/stage) ----------
        {
            int cur = 0;
#pragma unroll
            for (int k = 0; k < 5; ++k) {
                fft_stage<-1>(&bufs[cur][lf][0], &bufs[cur ^ 1][lf][0], lt, k);
                __syncthreads();
                cur ^= 1;
            }
        }
        // forward result in bufs[1]

        // ---------- rfft post-process + per-bin scan (regs) -> bufs[0] ----
#pragma unroll
        for (int f = 0; f < FCHUNK; ++f) {
            float2 Zk = bufs[1][f][P(tid)];
            float2 Zn = bufs[1][f][P((HALFN - tid) & (HALFN - 1))];
            float2 Fe = make_float2(0.5f * (Zk.x + Zn.x), 0.5f * (Zk.y - Zn.y));
            float2 Fo = make_float2(0.5f * (Zk.y + Zn.y), -0.5f * (Zk.x - Zn.x));
            float2 X  = cmul(make_float2(e2c, e2s), Fo);
            X.x += Fe.x; X.y += Fe.y;
            C.x = (X.x + C.x) * Treg;
            C.y = (X.y + C.y) * Treg;
            bufs[0][f][P(tid)] = C;
            if (tid == 0) {
                float Xny = Zk.x - Zk.y;            // from z[0]
                Cny.x = (Xny + Cny.x) * Tny;
                Cny.y = Cny.y * Tny;
                onys[f] = Cny;
            }
        }
        __syncthreads();

        // ---------- irfft pre-process: bufs[0] -> bufs[1] ----------
#pragma unroll
        for (int f = 0; f < FCHUNK; ++f) {
            float2 Om = bufs[0][f][P(tid)];
            float2 On = (tid == 0) ? onys[f] : bufs[0][f][P(HALFN - tid)];
            float2 Fe  = make_float2(0.5f * (Om.x + On.x), 0.5f * (Om.y - On.y));
            float2 num = make_float2(0.5f * (Om.x - On.x), 0.5f * (Om.y + On.y));
            float2 Fo  = cmul(make_float2(e2c, -e2s), num);  // e^{+i pi m/1024}
            bufs[1][f][P(tid)] = make_float2(Fe.x - Fo.y, Fe.y + Fo.x);
        }
        __syncthreads();

        // ---------- inverse FFTs (ping-pong) ----------
        {
            int cur = 1;
#pragma unroll
            for (int k = 0; k < 5; ++k) {
                fft_stage<1>(&bufs[cur][lf][0], &bufs[cur ^ 1][lf][0], lt, k);
                __syncthreads();
                cur ^= 1;
            }
        }
        // inverse result in bufs[0]

        // ---------- unpack + OLA + gain + tanh ----------
        {
            float sw0, cw0, sw1, cw1;
            __sincosf((PI / HALFN) * (float)tid, &sw0, &cw0);
            __sincosf((PI / HALFN) * (float)(HALFN + tid), &sw1, &cw1);
            float wU0 = 0.5f - 0.5f * cw0;
            float wU1 = 0.5f - 0.5f * cw1;
#pragma unroll
            for (int f = 0; f < FCHUNK; ++f) {
                int fr = ch * FCHUNK + f;
                float2 zlo = bufs[0][f][P(tid >> 1)];
                float2 zhi = bufs[0][f][P(512 + (tid >> 1))];
                float xs = (tid & 1) ? zlo.y : zlo.x;
                float xh = (tid & 1) ? zhi.y : zhi.x;
                float v  = tailr + xs * inv * wU0;
                io[base + (size_t)fr * HALFN + tid] = tanhf(g * v);
                tailr = xh * inv * wU1;
            }
        }
        __syncthreads();   // protect bufs[0] before next chunk's window-store
    }
}

// ---------------------------------------------------------------------------
extern "C" void kernel_launch(void* const* d_in, const int* in_sizes, int n_in,
                              void* d_out, int out_size, void* d_ws, size_t ws_size,
                              hipStream_t stream) {
    const float* x        = (const float*)d_in[0];   // (4,64,65536)
    const float* transfer = (const float*)d_in[1];   // (64,1025)
    const float* mixer    = (const float*)d_in[2];   // (64,64)
    const float* gain     = (const float*)d_in[3];   // (1,)
    float* out = (float*)d_out;                      // (4,64,65536)

    dim3 g1(TIME_N / TT, 4);
    mix_kernel<<<g1, 256, 0, stream>>>(x, mixer, out);

    stft_chain_kernel<<<256, 1024, 0, stream>>>(transfer, gain, out);
}

// Round 7
// 200.135 us; speedup vs baseline: 3.4346x; 1.2170x over previous
//
#include <hip/hip_runtime.h>
#include <math.h>

#define TIME_N 65536
#define WIN    2048
#define HALFN  1024
#define NBINS  1025
#define NFRAMES 64
#define FCHUNK 4
#define NCHUNK (NFRAMES / FCHUNK)   // 16

// ---------------------------------------------------------------------------
// Kernel 1: channel mixing  out[b,d,t] = sum_c x[b,c,t] * M[c,d]
// ---------------------------------------------------------------------------
#define TT 128
__global__ __launch_bounds__(256) void mix_kernel(const float* __restrict__ x,
                                                  const float* __restrict__ M,
                                                  float* __restrict__ out) {
    __shared__ float Ml[64 * 64];
    __shared__ float xt[64][136];
    const int b   = blockIdx.y;
    const int t0  = blockIdx.x * TT;
    const int tid = threadIdx.x;

    for (int i = tid; i < 64 * 64; i += 256) Ml[i] = M[i];

    for (int r = 0; r < 8; ++r) {
        int fi = tid + r * 256;
        int c  = fi >> 5;
        int t4 = fi & 31;
        float4 v = *reinterpret_cast<const float4*>(
            x + (size_t)(b * 64 + c) * TIME_N + t0 + t4 * 4);
        *reinterpret_cast<float4*>(&xt[c][t4 * 4]) = v;
    }
    __syncthreads();

    const int dq = tid >> 5;
    const int tq = tid & 31;

    float acc[8][4];
#pragma unroll
    for (int i = 0; i < 8; ++i)
#pragma unroll
        for (int j = 0; j < 4; ++j) acc[i][j] = 0.f;

    for (int c = 0; c < 64; ++c) {
        float xv[4];
#pragma unroll
        for (int j = 0; j < 4; ++j) xv[j] = xt[c][tq + 32 * j];
#pragma unroll
        for (int i = 0; i < 8; ++i) {
            float mv = Ml[c * 64 + dq * 8 + i];
#pragma unroll
            for (int j = 0; j < 4; ++j) acc[i][j] += xv[j] * mv;
        }
    }

#pragma unroll
    for (int i = 0; i < 8; ++i) {
        int d = dq * 8 + i;
        size_t baseo = (size_t)(b * 64 + d) * TIME_N + t0;
#pragma unroll
        for (int j = 0; j < 4; ++j) out[baseo + tq + 32 * j] = acc[i][j];
    }
}

// ---------------------------------------------------------------------------
// Kernel 2: fused STFT -> per-bin frame recursion -> iSTFT -> OLA -> tanh.
// 256 blocks x 512 threads (512-thread WGs demonstrably unlock VGPR>64, see
// round-1 vs rounds 2-6); FCHUNK=4 (4 FFTs x 128 lanes, 2 radix-4 butterflies
// per thread); ping-pong Stockham (1 barrier/stage); each thread owns 2 bins
// (2 scan carries), 2 output samples, 2 OLA-tail registers.
// ---------------------------------------------------------------------------
__device__ __forceinline__ int P(int i) { return i + (i >> 4); }   // pad-16
#define BUFSZ 1088   // P(1023) = 1086

__device__ __forceinline__ float2 cadd(float2 a, float2 b){return make_float2(a.x+b.x, a.y+b.y);}
__device__ __forceinline__ float2 csub(float2 a, float2 b){return make_float2(a.x-b.x, a.y-b.y);}
__device__ __forceinline__ float2 cmul(float2 a, float2 b){return make_float2(a.x*b.x - a.y*b.y, a.x*b.y + a.y*b.x);}

// One radix-4 self-sorting Stockham stage: read src, write dst (ping-pong).
// lt in [0,128): butterflies lt and lt+128.  k = stage (0..4).
template<int SGN>
__device__ __forceinline__ void fft_stage(const float2* __restrict__ src,
                                          float2* __restrict__ dst,
                                          int lt, int k) {
    const float PI2 = 6.2831853071795864769f;
    const int s = 1 << (2 * k);
    const int n = 1024 >> (2 * k);
#pragma unroll
    for (int r = 0; r < 2; ++r) {
        const int i = lt + r * 128;
        const int p = i >> (2 * k);
        const int q = i & (s - 1);
        float2 a  = src[P(i)];
        float2 bv = src[P(i + 256)];
        float2 cv = src[P(i + 512)];
        float2 dv = src[P(i + 768)];
        float ang = (float)SGN * PI2 * (float)p / (float)n;
        float sn, cs; __sincosf(ang, &sn, &cs);
        float2 w1 = make_float2(cs, sn);
        float2 w2 = cmul(w1, w1);
        float2 w3 = cmul(w1, w2);
        float2 apc = cadd(a, cv), amc = csub(a, cv);
        float2 bpd = cadd(bv, dv), bmd = csub(bv, dv);
        float2 sj = make_float2(-(float)SGN * bmd.y, (float)SGN * bmd.x);
        float2 y0 = cadd(apc, bpd);
        float2 y1 = cmul(w1, cadd(amc, sj));
        float2 y2 = cmul(w2, csub(apc, bpd));
        float2 y3 = cmul(w3, csub(amc, sj));
        int wb = q + 4 * s * p;
        dst[P(wb)]         = y0;
        dst[P(wb + s)]     = y1;
        dst[P(wb + 2 * s)] = y2;
        dst[P(wb + 3 * s)] = y3;
    }
}

__global__ __launch_bounds__(512) void stft_chain_kernel(
    const float* __restrict__ transfer,
    const float* __restrict__ gainp,
    float* __restrict__ io)
{
    __shared__ float2 bufs[2][FCHUNK][BUFSZ];   // ~69.6 KB ping-pong
    __shared__ float2 onys[FCHUNK];

    const int bd  = blockIdx.x;        // 0..255
    const int d   = bd & 63;
    const int tid = threadIdx.x;       // 0..511
    const int lf  = tid >> 7;          // frame within chunk (0..3)
    const int lt  = tid & 127;         // butterfly lane within that FFT
    const float g = gainp[0];
    const size_t base = (size_t)bd * TIME_N;
    const float PI  = 3.14159265358979323846f;
    const float inv = 1.0f / 1024.0f;

    // --- persistent per-thread state: 2 bins, 2 tails ---
    const float T0 = transfer[(size_t)d * NBINS + tid];
    const float T1 = transfer[(size_t)d * NBINS + tid + 512];
    const float Tny = (tid == 0) ? transfer[(size_t)d * NBINS + HALFN] : 0.f;
    float2 C0  = make_float2(0.f, 0.f);
    float2 C1  = make_float2(0.f, 0.f);
    float2 Cny = make_float2(0.f, 0.f);
    float tail0 = 0.f, tail1 = 0.f;

    for (int ch = 0; ch < NCHUNK; ++ch) {
        // ---------- load + window + store to bufs[0] ----------
        {
            float cw; float sw;
            __sincosf((PI / HALFN) * (float)(2 * tid), &sw, &cw);
            float wA0 = 0.5f - 0.5f * cw;
            __sincosf((PI / HALFN) * (float)(2 * tid + 1), &sw, &cw);
            float wB0 = 0.5f - 0.5f * cw;
            __sincosf((PI / HALFN) * (float)(1024 + 2 * tid), &sw, &cw);
            float wA1 = 0.5f - 0.5f * cw;
            __sincosf((PI / HALFN) * (float)(1025 + 2 * tid), &sw, &cw);
            float wB1 = 0.5f - 0.5f * cw;
#pragma unroll
            for (int f = 0; f < FCHUNK; ++f) {
                int fr = ch * FCHUNK + f;
                int t0 = fr * HALFN + 2 * tid;
                int t1 = t0 + 1024;
                float2 v0 = make_float2(0.f, 0.f), v1 = make_float2(0.f, 0.f);
                if (t0 < TIME_N) v0 = *reinterpret_cast<const float2*>(io + base + t0);
                if (t1 < TIME_N) v1 = *reinterpret_cast<const float2*>(io + base + t1);
                v0.x *= wA0; v0.y *= wB0;
                v1.x *= wA1; v1.y *= wB1;
                bufs[0][f][P(tid)]       = v0;
                bufs[0][f][P(tid + 512)] = v1;
            }
        }
        __syncthreads();

        // ---------- forward FFTs (ping-pong, 1 barrier/stage) ----------
        {
            int cur = 0;
#pragma unroll
            for (int k = 0; k < 5; ++k) {
                fft_stage<-1>(&bufs[cur][lf][0], &bufs[cur ^ 1][lf][0], lt, k);
                __syncthreads();
                cur ^= 1;
            }
        }
        // forward result in bufs[1]

        // ---------- rfft post-process + per-bin scan (2 bins/thread) ----
        {
            float sH0, cH0, sH1, cH1;
            __sincosf((PI / HALFN) * (float)tid, &sH0, &cH0);
            __sincosf((PI / HALFN) * (float)(tid + 512), &sH1, &cH1);
            // e2 = e^{-i pi k/1024} = (cH, -sH)
#pragma unroll
            for (int f = 0; f < FCHUNK; ++f) {
                // bin b0 = tid
                float2 Zk = bufs[1][f][P(tid)];
                float2 Zn = bufs[1][f][P((HALFN - tid) & (HALFN - 1))];
                float2 Fe = make_float2(0.5f * (Zk.x + Zn.x), 0.5f * (Zk.y - Zn.y));
                float2 Fo = make_float2(0.5f * (Zk.y + Zn.y), -0.5f * (Zk.x - Zn.x));
                float2 X  = cmul(make_float2(cH0, -sH0), Fo);
                X.x += Fe.x; X.y += Fe.y;
                C0.x = (X.x + C0.x) * T0;
                C0.y = (X.y + C0.y) * T0;
                bufs[0][f][P(tid)] = C0;
                if (tid == 0) {
                    float Xny = Zk.x - Zk.y;            // from z[0]
                    Cny.x = (Xny + Cny.x) * Tny;
                    Cny.y = Cny.y * Tny;
                    onys[f] = Cny;
                }
                // bin b1 = tid + 512
                float2 Zk1 = bufs[1][f][P(tid + 512)];
                float2 Zn1 = bufs[1][f][P(512 - tid)];
                float2 Fe1 = make_float2(0.5f * (Zk1.x + Zn1.x), 0.5f * (Zk1.y - Zn1.y));
                float2 Fo1 = make_float2(0.5f * (Zk1.y + Zn1.y), -0.5f * (Zk1.x - Zn1.x));
                float2 X1  = cmul(make_float2(cH1, -sH1), Fo1);
                X1.x += Fe1.x; X1.y += Fe1.y;
                C1.x = (X1.x + C1.x) * T1;
                C1.y = (X1.y + C1.y) * T1;
                bufs[0][f][P(tid + 512)] = C1;
            }
        }
        __syncthreads();

        // ---------- irfft pre-process: bufs[0] -> bufs[1] (2 bins/thread) --
        {
            float sH0, cH0, sH1, cH1;
            __sincosf((PI / HALFN) * (float)tid, &sH0, &cH0);
            __sincosf((PI / HALFN) * (float)(tid + 512), &sH1, &cH1);
            // w = e^{+i pi m/1024} = (cH, +sH)
#pragma unroll
            for (int f = 0; f < FCHUNK; ++f) {
                // m0 = tid
                float2 Om = bufs[0][f][P(tid)];
                float2 On = (tid == 0) ? onys[f] : bufs[0][f][P(HALFN - tid)];
                float2 Fe  = make_float2(0.5f * (Om.x + On.x), 0.5f * (Om.y - On.y));
                float2 num = make_float2(0.5f * (Om.x - On.x), 0.5f * (Om.y + On.y));
                float2 Fo  = cmul(make_float2(cH0, sH0), num);
                bufs[1][f][P(tid)] = make_float2(Fe.x - Fo.y, Fe.y + Fo.x);
                // m1 = tid + 512
                float2 Om1 = bufs[0][f][P(tid + 512)];
                float2 On1 = bufs[0][f][P(512 - tid)];
                float2 Fe1  = make_float2(0.5f * (Om1.x + On1.x), 0.5f * (Om1.y - On1.y));
                float2 num1 = make_float2(0.5f * (Om1.x - On1.x), 0.5f * (Om1.y + On1.y));
                float2 Fo1  = cmul(make_float2(cH1, sH1), num1);
                bufs[1][f][P(tid + 512)] = make_float2(Fe1.x - Fo1.y, Fe1.y + Fo1.x);
            }
        }
        __syncthreads();

        // ---------- inverse FFTs (ping-pong) ----------
        {
            int cur = 1;
#pragma unroll
            for (int k = 0; k < 5; ++k) {
                fft_stage<1>(&bufs[cur][lf][0], &bufs[cur ^ 1][lf][0], lt, k);
                __syncthreads();
                cur ^= 1;
            }
        }
        // inverse result in bufs[1] (started in bufs[1], odd # of swaps? no:
        // started cur=1, 5 stages: 1->0->1->0->1->0; result in bufs[0])

        // ---------- unpack + OLA + gain + tanh (2 samples + 2 tails) ------
        {
            float cw, sw;
            __sincosf((PI / HALFN) * (float)tid, &sw, &cw);
            float wU0 = 0.5f - 0.5f * cw;
            __sincosf((PI / HALFN) * (float)(tid + 512), &sw, &cw);
            float wU1 = 0.5f - 0.5f * cw;
            __sincosf((PI / HALFN) * (float)(1024 + tid), &sw, &cw);
            float wT0 = 0.5f - 0.5f * cw;
            __sincosf((PI / HALFN) * (float)(1536 + tid), &sw, &cw);
            float wT1 = 0.5f - 0.5f * cw;
#pragma unroll
            for (int f = 0; f < FCHUNK; ++f) {
                int fr = ch * FCHUNK + f;
                float2 zA = bufs[0][f][P(tid >> 1)];
                float2 zB = bufs[0][f][P(256 + (tid >> 1))];
                float2 zC = bufs[0][f][P(512 + (tid >> 1))];
                float2 zD = bufs[0][f][P(768 + (tid >> 1))];
                float xs0 = (tid & 1) ? zA.y : zA.x;
                float xs1 = (tid & 1) ? zB.y : zB.x;
                float xh0 = (tid & 1) ? zC.y : zC.x;
                float xh1 = (tid & 1) ? zD.y : zD.x;
                float v0 = tail0 + xs0 * inv * wU0;
                float v1 = tail1 + xs1 * inv * wU1;
                io[base + (size_t)fr * HALFN + tid]       = tanhf(g * v0);
                io[base + (size_t)fr * HALFN + tid + 512] = tanhf(g * v1);
                tail0 = xh0 * inv * wT0;
                tail1 = xh1 * inv * wT1;
            }
        }
        __syncthreads();   // protect bufs[0] before next chunk's window-store
    }
}

// ---------------------------------------------------------------------------
extern "C" void kernel_launch(void* const* d_in, const int* in_sizes, int n_in,
                              void* d_out, int out_size, void* d_ws, size_t ws_size,
                              hipStream_t stream) {
    const float* x        = (const float*)d_in[0];   // (4,64,65536)
    const float* transfer = (const float*)d_in[1];   // (64,1025)
    const float* mixer    = (const float*)d_in[2];   // (64,64)
    const float* gain     = (const float*)d_in[3];   // (1,)
    float* out = (float*)d_out;                      // (4,64,65536)

    dim3 g1(TIME_N / TT, 4);
    mix_kernel<<<g1, 256, 0, stream>>>(x, mixer, out);

    stft_chain_kernel<<<256, 512, 0, stream>>>(transfer, gain, out);
}